// Round 1
// baseline (44.801 us; speedup 1.0000x reference)
//
#include <hip/hip_runtime.h>
#include <cstdint>

namespace {

constexpr int kB   = 32;          // batches
constexpr int kN   = 131072;      // points per batch
constexpr int kC   = 6;           // channels
constexpr int TPB  = 256;         // threads per block (1 point / thread)
constexpr int BPB  = kN / TPB;    // 512 blocks per batch
constexpr int NBLK = kB * BPB;    // 16384 blocks total
constexpr int WAVES = TPB / 64;   // 4 waves per block

// Compute validity for point n of batch b; also returns the 6 row floats.
__device__ __forceinline__ bool point_valid(const float* __restrict__ pc,
                                            const float* __restrict__ tt,
                                            int b, int n,
                                            float2& a0, float2& a1, float2& a2) {
    const float* T = tt + b * 16;                 // 4x4 row-major
    const float2* row = (const float2*)(pc + ((size_t)b * kN + n) * kC);
    a0 = row[0];        // x, y
    a1 = row[1];        // z, nx
    a2 = row[2];        // ny, nz
    const float x = a0.x, y = a0.y, z = a1.x;
    const float nsum = (a1.y + a2.x) + a2.y;      // (nx+ny)+nz
    // rot[d][e] = T[d*4+e], trans[e] = T[e*4+3]
    const float px = x * T[0] + y * T[4] + z * T[8]  + T[3];
    const float py = x * T[1] + y * T[5] + z * T[9]  + T[7];
    const float pz = x * T[2] + y * T[6] + z * T[10] + T[11];
    return (px * px + py * py < 1.0f) && (pz < 1.0f) && (nsum != 0.0f);
}

// Pass 1: per-block valid count (+ optional per-wave 64-bit validity masks).
__global__ __launch_bounds__(TPB) void k_count(const float* __restrict__ pc,
                                               const float* __restrict__ tt,
                                               uint64_t* __restrict__ masks,
                                               int* __restrict__ blkCnt,
                                               int writeMask) {
    const int blk = blockIdx.x;
    const int b   = blk / BPB;
    const int k   = blk - b * BPB;
    const int tid = threadIdx.x;
    const int n   = k * TPB + tid;

    float2 a0, a1, a2;
    const bool valid = point_valid(pc, tt, b, n, a0, a1, a2);
    const uint64_t m = __ballot(valid);

    const int lane = tid & 63;
    const int wv   = tid >> 6;
    __shared__ int wc[WAVES];
    if (lane == 0) {
        if (writeMask) masks[(size_t)blk * WAVES + wv] = m;
        wc[wv] = __popcll(m);
    }
    __syncthreads();
    if (tid == 0) blkCnt[blk] = wc[0] + wc[1] + wc[2] + wc[3];
}

// Pass 2: per-batch exclusive scan over BPB(=512) block counts + batch totals.
__global__ __launch_bounds__(BPB) void k_scan(const int* __restrict__ blkCnt,
                                              int* __restrict__ blkPre,
                                              int* __restrict__ batchTot) {
    const int b = blockIdx.x;
    const int t = threadIdx.x;
    __shared__ int s[BPB];
    const int v = blkCnt[b * BPB + t];
    s[t] = v;
    __syncthreads();
    // Hillis–Steele inclusive scan
    for (int off = 1; off < BPB; off <<= 1) {
        int u = (t >= off) ? s[t - off] : 0;
        __syncthreads();
        s[t] += u;
        __syncthreads();
    }
    blkPre[b * BPB + t] = s[t] - v;       // exclusive
    if (t == BPB - 1) batchTot[b] = s[t]; // total valid in batch
}

// Pass 3: scatter. Valid rows -> compacted front (original order);
// invalid positions -> zeros in the tail. Every output row written once.
template <bool USE_MASK>
__global__ __launch_bounds__(TPB) void k_scatter(const float* __restrict__ pc,
                                                 const float* __restrict__ tt,
                                                 const uint64_t* __restrict__ masks,
                                                 const int* __restrict__ blkPre,
                                                 const int* __restrict__ batchTot,
                                                 float* __restrict__ out) {
    const int blk = blockIdx.x;
    const int b   = blk / BPB;
    const int k   = blk - b * BPB;
    const int tid = threadIdx.x;
    const int n   = k * TPB + tid;     // point index within batch
    const int lane = tid & 63;
    const int wv   = tid >> 6;

    uint64_t m;
    float2 a0, a1, a2;
    bool valid;
    if (USE_MASK) {
        m = masks[(size_t)blk * WAVES + wv];
        valid = (m >> lane) & 1ull;
    } else {
        valid = point_valid(pc, tt, b, n, a0, a1, a2);
        m = __ballot(valid);
    }

    __shared__ int wc[WAVES];
    if (lane == 0) wc[wv] = __popcll(m);
    __syncthreads();
    int waveBase = 0;
#pragma unroll
    for (int w = 0; w < WAVES - 1; ++w)
        if (w < wv) waveBase += wc[w];

    const int base   = blkPre[blk] + waveBase;                   // valid before this wave (in batch)
    const int before = __popcll(m & ((1ull << lane) - 1ull));    // valid before this lane (in wave)
    const int vcnt   = base + before;                            // valid strictly before point n
    const size_t outB = (size_t)b * kN;

    if (valid) {
        if (USE_MASK) {
            const float2* row = (const float2*)(pc + (outB + (size_t)n) * kC);
            a0 = row[0]; a1 = row[1]; a2 = row[2];
        }
        float2* o = (float2*)(out + (outB + (size_t)vcnt) * kC);
        o[0] = a0; o[1] = a1; o[2] = a2;
    } else {
        const int invRank = n - vcnt;
        const int dst = batchTot[b] + invRank;
        float2* o = (float2*)(out + (outB + (size_t)dst) * kC);
        const float2 zz = make_float2(0.0f, 0.0f);
        o[0] = zz; o[1] = zz; o[2] = zz;
    }
}

} // namespace

extern "C" void kernel_launch(void* const* d_in, const int* in_sizes, int n_in,
                              void* d_out, int out_size, void* d_ws, size_t ws_size,
                              hipStream_t stream) {
    const float* pc = (const float*)d_in[0];   // (32, 131072, 6) f32
    const float* tt = (const float*)d_in[1];   // (32, 4, 4) f32
    float* out = (float*)d_out;                // (32, 131072, 6) f32

    // Workspace layout
    const size_t maskBytes = (size_t)NBLK * WAVES * sizeof(uint64_t);  // 512 KiB
    const size_t intBytes  = (size_t)(2 * NBLK + kB) * sizeof(int);    // ~128 KiB
    const bool useMask = ws_size >= (maskBytes + intBytes);

    uint64_t* masks;
    int *blkCnt, *blkPre, *batchTot;
    if (useMask) {
        masks    = (uint64_t*)d_ws;
        blkCnt   = (int*)((char*)d_ws + maskBytes);
    } else {
        masks    = nullptr;
        blkCnt   = (int*)d_ws;
    }
    blkPre   = blkCnt + NBLK;
    batchTot = blkPre + NBLK;

    k_count<<<NBLK, TPB, 0, stream>>>(pc, tt, masks, blkCnt, useMask ? 1 : 0);
    k_scan<<<kB, BPB, 0, stream>>>(blkCnt, blkPre, batchTot);
    if (useMask) {
        k_scatter<true><<<NBLK, TPB, 0, stream>>>(pc, tt, masks, blkPre, batchTot, out);
    } else {
        k_scatter<false><<<NBLK, TPB, 0, stream>>>(pc, tt, nullptr, blkPre, batchTot, out);
    }
}